// Round 15
// baseline (585.735 us; speedup 1.0000x reference)
//
#include <hip/hip_runtime.h>

// Hetero GraphSAGE (3 layers, users<->movies) + JK-cat projection + BN-MLP edge scorer.
// R15 (on R14): attack aggregate's L2-miss wall (R14: FETCH 70MB/dispatch vs 15.4MB
// distinct table bytes -> movie-dst gathers from the 12.8MB user table thrash the
// 4MB/XCD L2):
//   - movie-dst aggregation runs 4 src-range passes (3.2MB L2-fit window/pass),
//     accumulators in registers across passes; user-dst path unchanged (its table
//     is 2.56MB, already L2-fit).
//   - scatter NPASS 8 -> 4 (halves edge re-reads, -4 launches).
// All other kernels byte-identical to R14.

namespace {

typedef unsigned int u32;
typedef unsigned short ushort_t;
typedef __attribute__((ext_vector_type(8))) short bfrag;   // 8 bf16 (4 VGPRs)
typedef __attribute__((ext_vector_type(4))) float f32x4;   // MFMA acc

constexpr int NUc = 100000;
constexpr int NMc = 20000;
constexpr int HD  = 64;
constexpr int NE  = 1000000;
constexpr int ELc = 500000;
constexpr int NL  = 3;
constexpr float BN_EPS = 1e-5f;

constexpr int CAPU = 48;    // slots per user bucket (mean deg 10)
constexpr int CAPM = 112;   // slots per movie bucket (mean deg 50)
constexpr int NPASS = 4;    // scatter passes (divides NUc and NMc)
constexpr int ASP = 4;      // aggregate src-range passes for movie-dst (divides NUc)

constexpr int PREP_BLOCKS = 6 * 24 + 16 + 4;  // = 164; MUST match PrepArgs::nblk sum
constexpr int STATS_BLOCKS = 512;

// ---- bf16 helpers (uint = 2 bf16, low ushort = even index) ----
__device__ __forceinline__ float bflo(u32 u) { return __uint_as_float(u << 16); }
__device__ __forceinline__ float bfhi(u32 u) { return __uint_as_float(u & 0xffff0000u); }
__device__ __forceinline__ u32 rbf(float f) {  // RNE round to bf16 bits (low 16)
  u32 u = __float_as_uint(f);
  return (u + 0x7fffu + ((u >> 16) & 1u)) >> 16;
}
__device__ __forceinline__ u32 packbf(float lo, float hi) { return rbf(lo) | (rbf(hi) << 16); }

__device__ __forceinline__ f32x4 mfma16(bfrag a, bfrag b, f32x4 c) {
  return __builtin_amdgcn_mfma_f32_16x16x32_bf16(a, b, c, 0, 0, 0);
}

// ---------------- slot-CSR build: 4 edges per thread ----------------

__global__ void scatter_pass_kernel(const int* __restrict__ eu, const int* __restrict__ em,
                                    int* __restrict__ cu, int* __restrict__ cm,
                                    int* __restrict__ su, int* __restrict__ sm,
                                    int ulo, int uhi, int mlo, int mhi) {
  int t4 = (blockIdx.x * 256 + threadIdx.x) * 4;
  if (t4 < NE) {   // NE % 4 == 0 -> all 4 edges valid
    int4 u4 = *(const int4*)(eu + t4);
    int4 m4 = *(const int4*)(em + t4);
#pragma unroll
    for (int j = 0; j < 4; j++) {
      int u = (j == 0) ? u4.x : (j == 1) ? u4.y : (j == 2) ? u4.z : u4.w;
      int m = (j == 0) ? m4.x : (j == 1) ? m4.y : (j == 2) ? m4.z : m4.w;
      if (u >= ulo && u < uhi) {
        int p = atomicAdd(&cu[u], 1);
        if (p < CAPU) su[(size_t)u * CAPU + p] = m;
      }
      if (m >= mlo && m < mhi) {
        int p = atomicAdd(&cm[m], 1);
        if (p < CAPM) sm[(size_t)m * CAPM + p] = u;
      }
    }
  }
}

// gather user embeddings + convert movie features, f32 -> bf16 (one launch)
__global__ void gatherconv_kernel(const int* __restrict__ n_id, const float* __restrict__ emb,
                                  u32* __restrict__ xu0,
                                  const float* __restrict__ mx, u32* __restrict__ xm0) {
  int t = blockIdx.x * 256 + threadIdx.x;
  if (t < NUc * 8) {
    int n = t >> 3, c = t & 7;
    const float* src = emb + (size_t)n_id[n] * HD + c * 8;
    float4 a = *(const float4*)src, b = *(const float4*)(src + 4);
    *(uint4*)(xu0 + (size_t)n * 32 + c * 4) =
        make_uint4(packbf(a.x, a.y), packbf(a.z, a.w), packbf(b.x, b.y), packbf(b.z, b.w));
  } else if (t < NUc * 8 + NMc * 8) {
    int tt = t - NUc * 8;
    int n = tt >> 3, c = tt & 7;
    const float* src = mx + (size_t)n * HD + c * 8;
    float4 a = *(const float4*)src, b = *(const float4*)(src + 4);
    *(uint4*)(xm0 + (size_t)n * 32 + c * 4) =
        make_uint4(packbf(a.x, a.y), packbf(a.z, a.w), packbf(b.x, b.y), packbf(b.z, b.w));
  }
}

// ---------------- fused mean aggregation ----------------
// 8 lanes per edge (f4 = lane&7 covers one uint4 = 8 bf16 cols); es = lane>>3 picks
// 1 of 8 concurrent edges. Movie-dst: 4 src-range passes so the gather window is
// 3.2MB (L2-fit); accumulators persist in registers across passes. User-dst: single
// pass, 2-deep unroll (table is 2.56MB, L2-fit).

__global__ void aggregate_fused_kernel(const int* __restrict__ cnt_m, const int* __restrict__ sm,
                                       const u32* __restrict__ xu, int xu_s,
                                       u32* __restrict__ agg_m,
                                       const int* __restrict__ cnt_u, const int* __restrict__ su,
                                       const u32* __restrict__ xm, int xm_s,
                                       u32* __restrict__ agg_u) {
  int gid  = blockIdx.x * 256 + threadIdx.x;
  int w    = gid >> 6;
  int lane = gid & 63;
  if (w >= NMc + NUc) return;
  int f4 = lane & 7;    // uint4 index within row (bf16 cols 8*f4..8*f4+7)
  int es = lane >> 3;   // edge slot 0..7
  float a0 = 0.f, a1 = 0.f, a2 = 0.f, a3 = 0.f;
  float a4 = 0.f, a5 = 0.f, a6 = 0.f, a7 = 0.f;
  u32* outp;
  int deg;
  if (w < NMc) {
    // movie dst: gather user rows, 4 src-range passes
    deg = min(cnt_m[w], CAPM);
    size_t base = (size_t)w * CAPM;
    outp = agg_m + (size_t)w * 32;
#pragma unroll
    for (int sp = 0; sp < ASP; sp++) {
      int lo = sp * (NUc / ASP), hi = lo + (NUc / ASP);
      for (int i = 0; i < deg; i += 8) {
        int e = i + es;
        if (e < deg) {
          int s = sm[base + e];
          if (s >= lo && s < hi) {
            uint4 v = *(const uint4*)(xu + (size_t)s * xu_s + 4 * f4);
            a0 += bflo(v.x); a1 += bfhi(v.x);
            a2 += bflo(v.y); a3 += bfhi(v.y);
            a4 += bflo(v.z); a5 += bfhi(v.z);
            a6 += bflo(v.w); a7 += bfhi(v.w);
          }
        }
      }
    }
  } else {
    // user dst: gather movie rows, single pass, 2-deep unroll
    int wu = w - NMc;
    deg = min(cnt_u[wu], CAPU);
    size_t base = (size_t)wu * CAPU;
    outp = agg_u + (size_t)wu * 32;
    int nfull = deg & ~15;
    int i = 0;
    for (; i < nfull; i += 16) {
      int e0 = su[base + i + es];
      int e1 = su[base + i + 8 + es];
      uint4 v0 = *(const uint4*)(xm + (size_t)e0 * xm_s + 4 * f4);
      uint4 v1 = *(const uint4*)(xm + (size_t)e1 * xm_s + 4 * f4);
      a0 += bflo(v0.x) + bflo(v1.x);
      a1 += bfhi(v0.x) + bfhi(v1.x);
      a2 += bflo(v0.y) + bflo(v1.y);
      a3 += bfhi(v0.y) + bfhi(v1.y);
      a4 += bflo(v0.z) + bflo(v1.z);
      a5 += bfhi(v0.z) + bfhi(v1.z);
      a6 += bflo(v0.w) + bflo(v1.w);
      a7 += bfhi(v0.w) + bfhi(v1.w);
    }
    for (; i < deg; i += 8) {
      int e = i + es;
      if (e < deg) {
        uint4 v = *(const uint4*)(xm + (size_t)su[base + e] * xm_s + 4 * f4);
        a0 += bflo(v.x); a1 += bfhi(v.x);
        a2 += bflo(v.y); a3 += bfhi(v.y);
        a4 += bflo(v.z); a5 += bfhi(v.z);
        a6 += bflo(v.w); a7 += bfhi(v.w);
      }
    }
  }
#pragma unroll
  for (int mask = 8; mask < 64; mask <<= 1) {
    a0 += __shfl_xor(a0, mask); a1 += __shfl_xor(a1, mask);
    a2 += __shfl_xor(a2, mask); a3 += __shfl_xor(a3, mask);
    a4 += __shfl_xor(a4, mask); a5 += __shfl_xor(a5, mask);
    a6 += __shfl_xor(a6, mask); a7 += __shfl_xor(a7, mask);
  }
  float inv = 1.f / fmaxf((float)deg, 1.f);
  if (es == 0) {
    uint4 o;
    o.x = packbf(a0 * inv, a1 * inv);
    o.y = packbf(a2 * inv, a3 * inv);
    o.z = packbf(a4 * inv, a5 * inv);
    o.w = packbf(a6 * inv, a7 * inv);
    *(uint4*)(outp + 4 * f4) = o;
  }
}

// ---------------- merged weight prep ----------------

struct PrepArgs {
  const float* src[8];
  u32* hi[8];
  u32* lo[8];
  int nblk[8];
};

__global__ __launch_bounds__(64) void prep_all_kernel(PrepArgs args) {
  int b = blockIdx.x;
  int e = 0;
  while (e < 8 && b >= args.nblk[e]) { b -= args.nblk[e]; e++; }
  if (e >= 8) return;  // grid/table miscount degrades to no-op, not a fault
  int l = threadIdx.x;
  u32 hi[4], lo[4];
  if (e < 7) {
    int m = b >> 3, s = (b >> 2) & 1, c = b & 3;
    int n  = c * 16 + (l & 15);
    int k0 = s * 32 + (l >> 4) * 8;
    const float* src = args.src[e] + (size_t)m * 4096;
#pragma unroll
    for (int p = 0; p < 4; p++) {
      float v0 = src[(k0 + 2 * p) * 64 + n];
      float v1 = src[(k0 + 2 * p + 1) * 64 + n];
      u32 h0 = rbf(v0), h1 = rbf(v1);
      float r0 = v0 - __uint_as_float(h0 << 16);
      float r1 = v1 - __uint_as_float(h1 << 16);
      hi[p] = h0 | (h1 << 16);
      lo[p] = rbf(r0) | (rbf(r1) << 16);
    }
    *(uint4*)(args.hi[e] + ((size_t)b * 64 + l) * 4) = make_uint4(hi[0], hi[1], hi[2], hi[3]);
    *(uint4*)(args.lo[e] + ((size_t)b * 64 + l) * 4) = make_uint4(lo[0], lo[1], lo[2], lo[3]);
  } else {
    int s = b >> 1, c = b & 1;
    int n  = c * 16 + (l & 15);
    int k0 = s * 32 + (l >> 4) * 8;
    const float* src = args.src[7];
#pragma unroll
    for (int p = 0; p < 4; p++) {
      float v0 = src[(k0 + 2 * p) * 32 + n];
      float v1 = src[(k0 + 2 * p + 1) * 32 + n];
      u32 h0 = rbf(v0), h1 = rbf(v1);
      float r0 = v0 - __uint_as_float(h0 << 16);
      float r1 = v1 - __uint_as_float(h1 << 16);
      hi[p] = h0 | (h1 << 16);
      lo[p] = rbf(r0) | (rbf(r1) << 16);
    }
    *(uint4*)(args.hi[7] + ((size_t)b * 64 + l) * 4) = make_uint4(hi[0], hi[1], hi[2], hi[3]);
    *(uint4*)(args.lo[7] + ((size_t)b * 64 + l) * 4) = make_uint4(lo[0], lo[1], lo[2], lo[3]);
  }
}

// frag offset (in u32) for kstep ks, colblock c (of 4), lane l
__device__ __forceinline__ size_t foff(int ks, int c, int l) {
  return ((size_t)((ks * 4 + c) * 64 + l)) * 4;
}
// frag offset for N=32 frags (2 colblocks)
__device__ __forceinline__ size_t foff32(int s, int c, int l) {
  return ((size_t)((s * 2 + c) * 64 + l)) * 4;
}

// ---------------- MFMA GEMM kernels: wave = 16 rows x 64 cols ----------------

__global__ __launch_bounds__(256) void sage_fused_kernel(
    int tm, int tu,
    const u32* __restrict__ agg_m, const u32* __restrict__ xm_prev, int sm_s,
    const u32* __restrict__ whiLm, const u32* __restrict__ wloLm,
    const u32* __restrict__ whiRm, const u32* __restrict__ wloRm,
    const float* __restrict__ bias_m, u32* __restrict__ out_m,
    const u32* __restrict__ agg_u, const u32* __restrict__ xu_prev, int su_s,
    const u32* __restrict__ whiLu, const u32* __restrict__ wloLu,
    const u32* __restrict__ whiRu, const u32* __restrict__ wloRu,
    const float* __restrict__ bias_u, u32* __restrict__ out_u) {
  int tile = blockIdx.x * 4 + (threadIdx.x >> 6);
  if (tile >= tm + tu) return;
  int lane = threadIdx.x & 63;
  const u32 *agg, *xin, *whiL, *wloL, *whiR, *wloR;
  const float* bias;
  u32* out;
  int xs;
  if (tile < tm) {
    agg = agg_m; xin = xm_prev; xs = sm_s;
    whiL = whiLm; wloL = wloLm; whiR = whiRm; wloR = wloRm;
    bias = bias_m; out = out_m;
  } else {
    tile -= tm;
    agg = agg_u; xin = xu_prev; xs = su_s;
    whiL = whiLu; wloL = wloLu; whiR = whiRu; wloR = wloRu;
    bias = bias_u; out = out_u;
  }
  int r  = tile * 16 + (lane & 15);
  int kq = lane >> 4;
  f32x4 acc[4];
#pragma unroll
  for (int c = 0; c < 4; c++) acc[c] = (f32x4){0.f, 0.f, 0.f, 0.f};
  const u32* arow0 = agg + (size_t)r * 32 + kq * 4;
  const u32* arow1 = xin + (size_t)r * xs + kq * 4;
#pragma unroll
  for (int s = 0; s < 2; s++) {
    bfrag a = *(const bfrag*)(arow0 + s * 16);
#pragma unroll
    for (int c = 0; c < 4; c++) {
      bfrag bh = *(const bfrag*)(whiL + foff(s, c, lane));
      bfrag bl = *(const bfrag*)(wloL + foff(s, c, lane));
      acc[c] = mfma16(a, bh, acc[c]);
      acc[c] = mfma16(a, bl, acc[c]);
    }
  }
#pragma unroll
  for (int s = 0; s < 2; s++) {
    bfrag a = *(const bfrag*)(arow1 + s * 16);
#pragma unroll
    for (int c = 0; c < 4; c++) {
      bfrag bh = *(const bfrag*)(whiR + foff(s, c, lane));
      bfrag bl = *(const bfrag*)(wloR + foff(s, c, lane));
      acc[c] = mfma16(a, bh, acc[c]);
      acc[c] = mfma16(a, bl, acc[c]);
    }
  }
  ushort_t* ob = (ushort_t*)out;
  int rowb = tile * 16 + (lane >> 4) * 4;
  int col0 = lane & 15;
#pragma unroll
  for (int c = 0; c < 4; c++) {
    float bb = bias[c * 16 + col0];
#pragma unroll
    for (int g = 0; g < 4; g++) {
      float v = fmaxf(acc[c][g] + bb, 0.f);
      ob[(size_t)(rowb + g) * 192 + c * 16 + col0] = (ushort_t)rbf(v);
    }
  }
}

__global__ __launch_bounds__(256) void proj_fused_kernel(
    int tu, int tm,
    const u32* __restrict__ xin_u, const u32* __restrict__ whi_u, const u32* __restrict__ wlo_u,
    const float* __restrict__ bias_u, u32* __restrict__ out_u,
    const u32* __restrict__ xin_m, const u32* __restrict__ whi_m, const u32* __restrict__ wlo_m,
    const float* __restrict__ bias_m, u32* __restrict__ out_m) {
  int tile = blockIdx.x * 4 + (threadIdx.x >> 6);
  if (tile >= tu + tm) return;
  int lane = threadIdx.x & 63;
  const u32 *xin, *whi, *wlo;
  const float* bias;
  u32* out;
  if (tile < tu) {
    xin = xin_u; whi = whi_u; wlo = wlo_u; bias = bias_u; out = out_u;
  } else {
    tile -= tu;
    xin = xin_m; whi = whi_m; wlo = wlo_m; bias = bias_m; out = out_m;
  }
  int r  = tile * 16 + (lane & 15);
  int kq = lane >> 4;
  f32x4 acc[4];
#pragma unroll
  for (int c = 0; c < 4; c++) acc[c] = (f32x4){0.f, 0.f, 0.f, 0.f};
  const u32* arow = xin + (size_t)r * 96 + kq * 4;
#pragma unroll
  for (int ks = 0; ks < 6; ks++) {
    bfrag a = *(const bfrag*)(arow + ks * 16);
#pragma unroll
    for (int c = 0; c < 4; c++) {
      bfrag bh = *(const bfrag*)(whi + foff(ks, c, lane));
      bfrag bl = *(const bfrag*)(wlo + foff(ks, c, lane));
      acc[c] = mfma16(a, bh, acc[c]);
      acc[c] = mfma16(a, bl, acc[c]);
    }
  }
  ushort_t* ob = (ushort_t*)out;
  int rowb = tile * 16 + (lane >> 4) * 4;
  int col0 = lane & 15;
#pragma unroll
  for (int c = 0; c < 4; c++) {
    float bb = bias[c * 16 + col0];
#pragma unroll
    for (int g = 0; g < 4; g++) {
      float v = acc[c][g] + bb;
      ob[(size_t)(rowb + g) * 64 + c * 16 + col0] = (ushort_t)rbf(v);
    }
  }
}

// y1 = cat(h_u[lu], h_m[lm]) @ W1 + b1; TWO tiles per wave (ntiles must be even).
__global__ __launch_bounds__(256) void cls1_mfma_kernel(
    int ntiles, const u32* __restrict__ hu, const u32* __restrict__ hm,
    const int* __restrict__ lu, const int* __restrict__ lm,
    const u32* __restrict__ whi, const u32* __restrict__ wlo,
    const float* __restrict__ b1, u32* __restrict__ y1) {
  int wid = blockIdx.x * 4 + (threadIdx.x >> 6);
  int t0 = wid * 2;
  if (t0 >= ntiles) return;  // ntiles even -> t0+1 also valid when t0 valid
  int lane = threadIdx.x & 63;
  int rit = lane & 15;
  int kq  = lane >> 4;
  int r0 = t0 * 16 + rit;
  int r1 = r0 + 16;
  int gu0 = lu[r0], gm0 = lm[r0];
  int gu1 = lu[r1], gm1 = lm[r1];
  f32x4 acc0[4], acc1[4];
#pragma unroll
  for (int c = 0; c < 4; c++) {
    acc0[c] = (f32x4){0.f, 0.f, 0.f, 0.f};
    acc1[c] = (f32x4){0.f, 0.f, 0.f, 0.f};
  }
  const u32* pu0 = hu + (size_t)gu0 * 32 + kq * 4;
  const u32* pm0 = hm + (size_t)gm0 * 32 + kq * 4;
  const u32* pu1 = hu + (size_t)gu1 * 32 + kq * 4;
  const u32* pm1 = hm + (size_t)gm1 * 32 + kq * 4;
#pragma unroll
  for (int s = 0; s < 2; s++) {
    bfrag au0 = *(const bfrag*)(pu0 + s * 16);
    bfrag au1 = *(const bfrag*)(pu1 + s * 16);
#pragma unroll
    for (int c = 0; c < 4; c++) {
      bfrag bh = *(const bfrag*)(whi + foff(s, c, lane));
      bfrag bl = *(const bfrag*)(wlo + foff(s, c, lane));
      acc0[c] = mfma16(au0, bh, acc0[c]);
      acc0[c] = mfma16(au0, bl, acc0[c]);
      acc1[c] = mfma16(au1, bh, acc1[c]);
      acc1[c] = mfma16(au1, bl, acc1[c]);
    }
  }
#pragma unroll
  for (int s = 0; s < 2; s++) {
    bfrag am0 = *(const bfrag*)(pm0 + s * 16);
    bfrag am1 = *(const bfrag*)(pm1 + s * 16);
#pragma unroll
    for (int c = 0; c < 4; c++) {
      bfrag bh = *(const bfrag*)(whi + foff(2 + s, c, lane));
      bfrag bl = *(const bfrag*)(wlo + foff(2 + s, c, lane));
      acc0[c] = mfma16(am0, bh, acc0[c]);
      acc0[c] = mfma16(am0, bl, acc0[c]);
      acc1[c] = mfma16(am1, bh, acc1[c]);
      acc1[c] = mfma16(am1, bl, acc1[c]);
    }
  }
  ushort_t* ob = (ushort_t*)y1;
  int col0 = lane & 15;
  int rowb0 = t0 * 16 + kq * 4;
  int rowb1 = rowb0 + 16;
#pragma unroll
  for (int c = 0; c < 4; c++) {
    float bb = b1[c * 16 + col0];
#pragma unroll
    for (int g = 0; g < 4; g++) {
      float v0 = acc0[c][g] + bb;
      float v1 = acc1[c][g] + bb;
      ob[(size_t)(rowb0 + g) * 64 + c * 16 + col0] = (ushort_t)rbf(v0);
      ob[(size_t)(rowb1 + g) * 64 + c * 16 + col0] = (ushort_t)rbf(v1);
    }
  }
}

// y2 = relu(BN1(y1)) @ W2 + b2 via MFMA; BN applied in-register to A-frags.
__global__ __launch_bounds__(256) void cls2_mfma_kernel(
    int ntiles, const u32* __restrict__ y1,
    const float* __restrict__ scale1, const float* __restrict__ shift1,
    const u32* __restrict__ whi, const u32* __restrict__ wlo,
    const float* __restrict__ b2, u32* __restrict__ y2) {
  int tile = blockIdx.x * 4 + (threadIdx.x >> 6);
  if (tile >= ntiles) return;
  int lane = threadIdx.x & 63;
  int r  = tile * 16 + (lane & 15);
  int kq = lane >> 4;
  f32x4 acc[2];
  acc[0] = (f32x4){0.f, 0.f, 0.f, 0.f};
  acc[1] = (f32x4){0.f, 0.f, 0.f, 0.f};
  const u32* xrow = y1 + (size_t)r * 32 + kq * 4;
#pragma unroll
  for (int s = 0; s < 2; s++) {
    uint4 q = *(const uint4*)(xrow + s * 16);
    int kb = s * 32 + kq * 8;
    float a0 = fmaxf(bflo(q.x) * scale1[kb + 0] + shift1[kb + 0], 0.f);
    float a1 = fmaxf(bfhi(q.x) * scale1[kb + 1] + shift1[kb + 1], 0.f);
    float a2 = fmaxf(bflo(q.y) * scale1[kb + 2] + shift1[kb + 2], 0.f);
    float a3 = fmaxf(bfhi(q.y) * scale1[kb + 3] + shift1[kb + 3], 0.f);
    float a4 = fmaxf(bflo(q.z) * scale1[kb + 4] + shift1[kb + 4], 0.f);
    float a5 = fmaxf(bfhi(q.z) * scale1[kb + 5] + shift1[kb + 5], 0.f);
    float a6 = fmaxf(bflo(q.w) * scale1[kb + 6] + shift1[kb + 6], 0.f);
    float a7 = fmaxf(bfhi(q.w) * scale1[kb + 7] + shift1[kb + 7], 0.f);
    uint4 pa = make_uint4(packbf(a0, a1), packbf(a2, a3), packbf(a4, a5), packbf(a6, a7));
    bfrag a = *(bfrag*)&pa;
#pragma unroll
    for (int c = 0; c < 2; c++) {
      bfrag bh = *(const bfrag*)(whi + foff32(s, c, lane));
      bfrag bl = *(const bfrag*)(wlo + foff32(s, c, lane));
      acc[c] = mfma16(a, bh, acc[c]);
      acc[c] = mfma16(a, bl, acc[c]);
    }
  }
  ushort_t* ob = (ushort_t*)y2;
  int rowb = tile * 16 + (lane >> 4) * 4;
  int col0 = lane & 15;
#pragma unroll
  for (int c = 0; c < 2; c++) {
    float bb = b2[c * 16 + col0];
#pragma unroll
    for (int g = 0; g < 4; g++) {
      float v = acc[c][g] + bb;
      ob[(size_t)(rowb + g) * 32 + c * 16 + col0] = (ushort_t)rbf(v);
    }
  }
}

// ---------------- BN stats (de-spilled streamer) / finalize / cls3 ----------------

template <int CU>
__global__ __launch_bounds__(256) void stats_fast_kernel(const u32* __restrict__ y, int nrows,
                                                         float* __restrict__ sum,
                                                         float* __restrict__ ssq) {
  constexpr int TPR = CU / 4;      // threads per row (one uint4 each)
  constexpr int RPI = 256 / TPR;   // rows per block per iteration
  int t = threadIdx.x;
  int q  = t % TPR;                // uint4 index within row (bf16 cols q*8..q*8+7)
  int rg = t / TPR;
  float4 sA = {0.f, 0.f, 0.f, 0.f}, sB = {0.f, 0.f, 0.f, 0.f};
  float4 qA = {0.f, 0.f, 0.f, 0.f}, qB = {0.f, 0.f, 0.f, 0.f};
  for (int row = blockIdx.x * RPI + rg; row < nrows; row += gridDim.x * RPI) {
    uint4 v = *(const uint4*)(y + (size_t)row * CU + q * 4);
    float a0 = bflo(v.x), a1 = bfhi(v.x), a2 = bflo(v.y), a3 = bfhi(v.y);
    float a4 = bflo(v.z), a5 = bfhi(v.z), a6 = bflo(v.w), a7 = bfhi(v.w);
    sA.x += a0; qA.x += a0 * a0;
    sA.y += a1; qA.y += a1 * a1;
    sA.z += a2; qA.z += a2 * a2;
    sA.w += a3; qA.w += a3 * a3;
    sB.x += a4; qB.x += a4 * a4;
    sB.y += a5; qB.y += a5 * a5;
    sB.z += a6; qB.z += a6 * a6;
    sB.w += a7; qB.w += a7 * a7;
  }
#pragma unroll
  for (int mask = TPR; mask < 64; mask <<= 1) {
    sA.x += __shfl_xor(sA.x, mask); sA.y += __shfl_xor(sA.y, mask);
    sA.z += __shfl_xor(sA.z, mask); sA.w += __shfl_xor(sA.w, mask);
    sB.x += __shfl_xor(sB.x, mask); sB.y += __shfl_xor(sB.y, mask);
    sB.z += __shfl_xor(sB.z, mask); sB.w += __shfl_xor(sB.w, mask);
    qA.x += __shfl_xor(qA.x, mask); qA.y += __shfl_xor(qA.y, mask);
    qA.z += __shfl_xor(qA.z, mask); qA.w += __shfl_xor(qA.w, mask);
    qB.x += __shfl_xor(qB.x, mask); qB.y += __shfl_xor(qB.y, mask);
    qB.z += __shfl_xor(qB.z, mask); qB.w += __shfl_xor(qB.w, mask);
  }
  __shared__ float part[4][TPR][16];
  int wv = t >> 6, lane = t & 63;
  if (lane < TPR) {
    float* p = part[wv][lane];
    p[0] = sA.x; p[1] = sA.y; p[2] = sA.z; p[3] = sA.w;
    p[4] = sB.x; p[5] = sB.y; p[6] = sB.z; p[7] = sB.w;
    p[8] = qA.x; p[9] = qA.y; p[10] = qA.z; p[11] = qA.w;
    p[12] = qB.x; p[13] = qB.y; p[14] = qB.z; p[15] = qB.w;
  }
  __syncthreads();
  if (t < TPR * 16) {
    int qq = t >> 4, j = t & 15;
    float v = part[0][qq][j] + part[1][qq][j] + part[2][qq][j] + part[3][qq][j];
    if (j < 8) atomicAdd(&sum[qq * 8 + j], v);
    else       atomicAdd(&ssq[qq * 8 + (j - 8)], v);
  }
}

__global__ void bn_finalize_kernel(const float* __restrict__ sum, const float* __restrict__ ssq,
                                   const float* __restrict__ g, const float* __restrict__ be,
                                   int ncols, float inv_n,
                                   float* __restrict__ scale, float* __restrict__ shift) {
  int t = threadIdx.x;
  if (t < ncols) {
    float m = sum[t] * inv_n;
    float v = ssq[t] * inv_n - m * m;   // biased variance, as torch BN training-mode
    float rstd = rsqrtf(v + BN_EPS);
    float sc = g[t] * rstd;
    scale[t] = sc;
    shift[t] = be[t] - m * sc;
  }
}

__global__ void cls3_kernel(const u32* __restrict__ y2, const float* __restrict__ scale2,
                            const float* __restrict__ shift2, const float* __restrict__ W3,
                            const float* __restrict__ b3, float* __restrict__ outp) {
  int r = blockIdx.x * 256 + threadIdx.x;
  if (r >= ELc) return;
  const u32* yr = y2 + (size_t)r * 16;
  float s = b3[0];
#pragma unroll
  for (int j = 0; j < 16; j++) {
    u32 u = yr[j];
    float v0 = fmaxf(bflo(u) * scale2[2 * j] + shift2[2 * j], 0.f);
    float v1 = fmaxf(bfhi(u) * scale2[2 * j + 1] + shift2[2 * j + 1], 0.f);
    s += v0 * W3[2 * j] + v1 * W3[2 * j + 1];
  }
  outp[r] = s;
}

}  // namespace

extern "C" void kernel_launch(void* const* d_in, const int* in_sizes, int n_in,
                              void* d_out, int out_size, void* d_ws, size_t ws_size,
                              hipStream_t stream) {
  const int*   n_id    = (const int*)d_in[0];
  const float* movie_x = (const float*)d_in[1];
  const int*   eu      = (const int*)d_in[2];
  const int*   em      = (const int*)d_in[3];
  const int*   lu      = (const int*)d_in[4];
  const int*   lm      = (const int*)d_in[5];
  const float* uemb    = (const float*)d_in[6];
  const float* Wl_um   = (const float*)d_in[7];
  const float* b_um    = (const float*)d_in[8];
  const float* Wr_um   = (const float*)d_in[9];
  const float* Wl_mu   = (const float*)d_in[10];
  const float* b_mu    = (const float*)d_in[11];
  const float* Wr_mu   = (const float*)d_in[12];
  const float* puW     = (const float*)d_in[13];
  const float* pub     = (const float*)d_in[14];
  const float* pmW     = (const float*)d_in[15];
  const float* pmb     = (const float*)d_in[16];
  const float* W1      = (const float*)d_in[17];
  const float* b1      = (const float*)d_in[18];
  const float* g1      = (const float*)d_in[19];
  const float* be1     = (const float*)d_in[20];
  const float* W2      = (const float*)d_in[21];
  const float* b2      = (const float*)d_in[22];
  const float* g2      = (const float*)d_in[23];
  const float* be2     = (const float*)d_in[24];
  const float* W3      = (const float*)d_in[25];
  const float* b3      = (const float*)d_in[26];
  float* outp = (float*)d_out;

  u32* ws = (u32*)d_ws;
  size_t o = 0;
  u32* xu0    = ws + o; o += (size_t)NUc * 32;
  u32* xm0    = ws + o; o += (size_t)NMc * 32;
  u32* outs_u = ws + o; o += (size_t)NUc * 96;
  u32* outs_m = ws + o; o += (size_t)NMc * 96;
  u32* agg_u  = ws + o; o += (size_t)NUc * 32;
  u32* agg_m  = ws + o; o += (size_t)NMc * 32;
  u32* y1 = ws;  // bf16 [EL][64] = 16M u32, overlays conv region (dead before cls1)
  u32* y2     = ws + o; o += (size_t)ELc * 16;
  u32* h_u    = ws + o; o += (size_t)NUc * 32;
  u32* h_m    = ws + o; o += (size_t)NMc * 32;
  int* su     = (int*)(ws + o); o += (size_t)NUc * CAPU;
  int* sm     = (int*)(ws + o); o += (size_t)NMc * CAPM;
  int* cnt_u  = (int*)(ws + o); o += NUc;        // cnt_u, cnt_m, stats contiguous:
  int* cnt_m  = (int*)(ws + o); o += NMc;        //   one memset covers all three
  float* stats = (float*)(ws + o); o += 512;
  u32* frWlum_h = ws + o; o += 3 * 2048;  u32* frWlum_l = ws + o; o += 3 * 2048;
  u32* frWrum_h = ws + o; o += 3 * 2048;  u32* frWrum_l = ws + o; o += 3 * 2048;
  u32* frWlmu_h = ws + o; o += 3 * 2048;  u32* frWlmu_l = ws + o; o += 3 * 2048;
  u32* frWrmu_h = ws + o; o += 3 * 2048;  u32* frWrmu_l = ws + o; o += 3 * 2048;
  u32* frPu_h   = ws + o; o += 3 * 2048;  u32* frPu_l   = ws + o; o += 3 * 2048;
  u32* frPm_h   = ws + o; o += 3 * 2048;  u32* frPm_l   = ws + o; o += 3 * 2048;
  u32* frW1_h   = ws + o; o += 2 * 2048;  u32* frW1_l   = ws + o; o += 2 * 2048;
  u32* frW2_h   = ws + o; o += 1024;      u32* frW2_l   = ws + o; o += 1024;
  if (ws_size < o * sizeof(u32)) return;  // ws too small -> leave zeros (diagnostic)

  float* sum1 = stats,        *ssq1 = stats + 64;
  float* sum2 = stats + 128,  *ssq2 = stats + 160;
  float* scale1 = stats + 192, *shift1 = stats + 256;
  float* scale2 = stats + 320, *shift2 = stats + 352;

  hipMemsetAsync(cnt_u, 0, (NUc + NMc + 192) * sizeof(int), stream);

  PrepArgs pa;
  pa.src[0] = Wl_um; pa.hi[0] = frWlum_h; pa.lo[0] = frWlum_l; pa.nblk[0] = 24;
  pa.src[1] = Wr_um; pa.hi[1] = frWrum_h; pa.lo[1] = frWrum_l; pa.nblk[1] = 24;
  pa.src[2] = Wl_mu; pa.hi[2] = frWlmu_h; pa.lo[2] = frWlmu_l; pa.nblk[2] = 24;
  pa.src[3] = Wr_mu; pa.hi[3] = frWrmu_h; pa.lo[3] = frWrmu_l; pa.nblk[3] = 24;
  pa.src[4] = puW;   pa.hi[4] = frPu_h;   pa.lo[4] = frPu_l;   pa.nblk[4] = 24;
  pa.src[5] = pmW;   pa.hi[5] = frPm_h;   pa.lo[5] = frPm_l;   pa.nblk[5] = 24;
  pa.src[6] = W1;    pa.hi[6] = frW1_h;   pa.lo[6] = frW1_l;   pa.nblk[6] = 16;
  pa.src[7] = W2;    pa.hi[7] = frW2_h;   pa.lo[7] = frW2_l;   pa.nblk[7] = 4;
  prep_all_kernel<<<PREP_BLOCKS, 64, 0, stream>>>(pa);

  int eb4 = (NE / 4 + 255) / 256;   // 4 edges per thread (NE % 4 == 0)
  for (int p = 0; p < NPASS; p++) {
    scatter_pass_kernel<<<eb4, 256, 0, stream>>>(
        eu, em, cnt_u, cnt_m, su, sm,
        p * (NUc / NPASS), (p + 1) * (NUc / NPASS),
        p * (NMc / NPASS), (p + 1) * (NMc / NPASS));
  }
  gatherconv_kernel<<<((NUc + NMc) * 8 + 255) / 256, 256, 0, stream>>>(
      n_id, uemb, xu0, movie_x, xm0);

  int tu = NUc / 16, tm = NMc / 16;   // 6250, 1250 (exact)
  int agg_grid = ((NMc + NUc) * 64 + 255) / 256;
  for (int i = 0; i < NL; i++) {
    const u32* xu_prev = (i == 0) ? xu0 : (outs_u + (size_t)(i - 1) * 32);
    const u32* xm_prev = (i == 0) ? xm0 : (outs_m + (size_t)(i - 1) * 32);
    int su_s = (i == 0) ? 32 : 96;
    int sm_s = (i == 0) ? 32 : 96;
    aggregate_fused_kernel<<<agg_grid, 256, 0, stream>>>(
        cnt_m, sm, xu_prev, su_s, agg_m,
        cnt_u, su, xm_prev, sm_s, agg_u);
    sage_fused_kernel<<<(tm + tu + 3) / 4, 256, 0, stream>>>(
        tm, tu,
        agg_m, xm_prev, sm_s,
        frWlum_h + (size_t)i * 2048, frWlum_l + (size_t)i * 2048,
        frWrum_h + (size_t)i * 2048, frWrum_l + (size_t)i * 2048,
        b_um + (size_t)i * HD, outs_m + (size_t)i * 32,
        agg_u, xu_prev, su_s,
        frWlmu_h + (size_t)i * 2048, frWlmu_l + (size_t)i * 2048,
        frWrmu_h + (size_t)i * 2048, frWrmu_l + (size_t)i * 2048,
        b_mu + (size_t)i * HD, outs_u + (size_t)i * 32);
  }

  proj_fused_kernel<<<(tu + tm + 3) / 4, 256, 0, stream>>>(
      tu, tm, outs_u, frPu_h, frPu_l, pub, h_u,
      outs_m, frPm_h, frPm_l, pmb, h_m);

  int tl = ELc / 16;  // 31250 (exact, even)
  cls1_mfma_kernel<<<(tl / 2 + 3) / 4, 256, 0, stream>>>(tl, h_u, h_m, lu, lm, frW1_h, frW1_l, b1, y1);
  stats_fast_kernel<32><<<STATS_BLOCKS, 256, 0, stream>>>(y1, ELc, sum1, ssq1);
  bn_finalize_kernel<<<1, 64, 0, stream>>>(sum1, ssq1, g1, be1, 64, 1.f / ELc, scale1, shift1);
  cls2_mfma_kernel<<<(tl + 3) / 4, 256, 0, stream>>>(tl, y1, scale1, shift1, frW2_h, frW2_l, b2, y2);
  stats_fast_kernel<16><<<STATS_BLOCKS, 256, 0, stream>>>(y2, ELc, sum2, ssq2);
  bn_finalize_kernel<<<1, 64, 0, stream>>>(sum2, ssq2, g2, be2, 32, 1.f / ELc, scale2, shift2);
  cls3_kernel<<<(ELc + 255) / 256, 256, 0, stream>>>(y2, scale2, shift2, W3, b3, outp);
}

// Round 16
// 489.007 us; speedup vs baseline: 1.1978x; 1.1978x over previous
//
#include <hip/hip_runtime.h>

// Hetero GraphSAGE (3 layers, users<->movies) + JK-cat projection + BN-MLP edge scorer.
// R16 = R15 with aggregate_fused reverted to the R14 single-pass form (R15's
// src-range passes were falsified: FETCH unchanged at 72MB, +33us/dispatch from
// 4x index re-scan; blocks don't pass-synchronize). KEEPS R15's scatter NPASS=4,
// which the R15 ledger shows saved ~75us. All else identical to R14/R15.

namespace {

typedef unsigned int u32;
typedef unsigned short ushort_t;
typedef __attribute__((ext_vector_type(8))) short bfrag;   // 8 bf16 (4 VGPRs)
typedef __attribute__((ext_vector_type(4))) float f32x4;   // MFMA acc

constexpr int NUc = 100000;
constexpr int NMc = 20000;
constexpr int HD  = 64;
constexpr int NE  = 1000000;
constexpr int ELc = 500000;
constexpr int NL  = 3;
constexpr float BN_EPS = 1e-5f;

constexpr int CAPU = 48;    // slots per user bucket (mean deg 10)
constexpr int CAPM = 112;   // slots per movie bucket (mean deg 50)
constexpr int NPASS = 4;    // scatter passes (divides NUc and NMc)

constexpr int PREP_BLOCKS = 6 * 24 + 16 + 4;  // = 164; MUST match PrepArgs::nblk sum
constexpr int STATS_BLOCKS = 512;

// ---- bf16 helpers (uint = 2 bf16, low ushort = even index) ----
__device__ __forceinline__ float bflo(u32 u) { return __uint_as_float(u << 16); }
__device__ __forceinline__ float bfhi(u32 u) { return __uint_as_float(u & 0xffff0000u); }
__device__ __forceinline__ u32 rbf(float f) {  // RNE round to bf16 bits (low 16)
  u32 u = __float_as_uint(f);
  return (u + 0x7fffu + ((u >> 16) & 1u)) >> 16;
}
__device__ __forceinline__ u32 packbf(float lo, float hi) { return rbf(lo) | (rbf(hi) << 16); }

__device__ __forceinline__ f32x4 mfma16(bfrag a, bfrag b, f32x4 c) {
  return __builtin_amdgcn_mfma_f32_16x16x32_bf16(a, b, c, 0, 0, 0);
}

// ---------------- slot-CSR build: 4 edges per thread ----------------

__global__ void scatter_pass_kernel(const int* __restrict__ eu, const int* __restrict__ em,
                                    int* __restrict__ cu, int* __restrict__ cm,
                                    int* __restrict__ su, int* __restrict__ sm,
                                    int ulo, int uhi, int mlo, int mhi) {
  int t4 = (blockIdx.x * 256 + threadIdx.x) * 4;
  if (t4 < NE) {   // NE % 4 == 0 -> all 4 edges valid
    int4 u4 = *(const int4*)(eu + t4);
    int4 m4 = *(const int4*)(em + t4);
#pragma unroll
    for (int j = 0; j < 4; j++) {
      int u = (j == 0) ? u4.x : (j == 1) ? u4.y : (j == 2) ? u4.z : u4.w;
      int m = (j == 0) ? m4.x : (j == 1) ? m4.y : (j == 2) ? m4.z : m4.w;
      if (u >= ulo && u < uhi) {
        int p = atomicAdd(&cu[u], 1);
        if (p < CAPU) su[(size_t)u * CAPU + p] = m;
      }
      if (m >= mlo && m < mhi) {
        int p = atomicAdd(&cm[m], 1);
        if (p < CAPM) sm[(size_t)m * CAPM + p] = u;
      }
    }
  }
}

// gather user embeddings + convert movie features, f32 -> bf16 (one launch)
__global__ void gatherconv_kernel(const int* __restrict__ n_id, const float* __restrict__ emb,
                                  u32* __restrict__ xu0,
                                  const float* __restrict__ mx, u32* __restrict__ xm0) {
  int t = blockIdx.x * 256 + threadIdx.x;
  if (t < NUc * 8) {
    int n = t >> 3, c = t & 7;
    const float* src = emb + (size_t)n_id[n] * HD + c * 8;
    float4 a = *(const float4*)src, b = *(const float4*)(src + 4);
    *(uint4*)(xu0 + (size_t)n * 32 + c * 4) =
        make_uint4(packbf(a.x, a.y), packbf(a.z, a.w), packbf(b.x, b.y), packbf(b.z, b.w));
  } else if (t < NUc * 8 + NMc * 8) {
    int tt = t - NUc * 8;
    int n = tt >> 3, c = tt & 7;
    const float* src = mx + (size_t)n * HD + c * 8;
    float4 a = *(const float4*)src, b = *(const float4*)(src + 4);
    *(uint4*)(xm0 + (size_t)n * 32 + c * 4) =
        make_uint4(packbf(a.x, a.y), packbf(a.z, a.w), packbf(b.x, b.y), packbf(b.z, b.w));
  }
}

// ---------------- fused mean aggregation (R14 form): uint4 gathers, 8 edges/wave slot ----------------
// 8 lanes per edge: f4 = lane&7 covers u32s 4*f4..4*f4+3 via one uint4 (16B) load;
// es = lane>>3 picks 1 of 8 concurrent edges; 2-deep unroll -> 16 loads in flight.
// Cross-edge reduce: shfl_xor masks 8, 16, 32.

__global__ void aggregate_fused_kernel(const int* __restrict__ cnt_m, const int* __restrict__ sm,
                                       const u32* __restrict__ xu, int xu_s,
                                       u32* __restrict__ agg_m,
                                       const int* __restrict__ cnt_u, const int* __restrict__ su,
                                       const u32* __restrict__ xm, int xm_s,
                                       u32* __restrict__ agg_u) {
  int gid  = blockIdx.x * 256 + threadIdx.x;
  int w    = gid >> 6;
  int lane = gid & 63;
  if (w >= NMc + NUc) return;
  const int* src;
  const u32* table;
  u32* outp;
  int stride, deg;
  size_t base;
  if (w < NMc) {
    deg = min(cnt_m[w], CAPM);
    base = (size_t)w * CAPM;
    src = sm; table = xu; stride = xu_s;
    outp = agg_m + (size_t)w * 32;
  } else {
    int wu = w - NMc;
    deg = min(cnt_u[wu], CAPU);
    base = (size_t)wu * CAPU;
    src = su; table = xm; stride = xm_s;
    outp = agg_u + (size_t)wu * 32;
  }
  int f4 = lane & 7;    // uint4 index within row (bf16 cols 8*f4..8*f4+7)
  int es = lane >> 3;   // edge slot 0..7
  float a0 = 0.f, a1 = 0.f, a2 = 0.f, a3 = 0.f;
  float a4 = 0.f, a5 = 0.f, a6 = 0.f, a7 = 0.f;
  int nfull = deg & ~15;
  int i = 0;
  for (; i < nfull; i += 16) {
    int e0 = src[base + i + es];
    int e1 = src[base + i + 8 + es];
    uint4 v0 = *(const uint4*)(table + (size_t)e0 * stride + 4 * f4);
    uint4 v1 = *(const uint4*)(table + (size_t)e1 * stride + 4 * f4);
    a0 += bflo(v0.x) + bflo(v1.x);
    a1 += bfhi(v0.x) + bfhi(v1.x);
    a2 += bflo(v0.y) + bflo(v1.y);
    a3 += bfhi(v0.y) + bfhi(v1.y);
    a4 += bflo(v0.z) + bflo(v1.z);
    a5 += bfhi(v0.z) + bfhi(v1.z);
    a6 += bflo(v0.w) + bflo(v1.w);
    a7 += bfhi(v0.w) + bfhi(v1.w);
  }
  for (; i < deg; i += 8) {
    int e = i + es;
    if (e < deg) {
      uint4 v = *(const uint4*)(table + (size_t)src[base + e] * stride + 4 * f4);
      a0 += bflo(v.x); a1 += bfhi(v.x);
      a2 += bflo(v.y); a3 += bfhi(v.y);
      a4 += bflo(v.z); a5 += bfhi(v.z);
      a6 += bflo(v.w); a7 += bfhi(v.w);
    }
  }
#pragma unroll
  for (int mask = 8; mask < 64; mask <<= 1) {
    a0 += __shfl_xor(a0, mask); a1 += __shfl_xor(a1, mask);
    a2 += __shfl_xor(a2, mask); a3 += __shfl_xor(a3, mask);
    a4 += __shfl_xor(a4, mask); a5 += __shfl_xor(a5, mask);
    a6 += __shfl_xor(a6, mask); a7 += __shfl_xor(a7, mask);
  }
  float inv = 1.f / fmaxf((float)deg, 1.f);
  if (es == 0) {
    uint4 o;
    o.x = packbf(a0 * inv, a1 * inv);
    o.y = packbf(a2 * inv, a3 * inv);
    o.z = packbf(a4 * inv, a5 * inv);
    o.w = packbf(a6 * inv, a7 * inv);
    *(uint4*)(outp + 4 * f4) = o;
  }
}

// ---------------- merged weight prep ----------------

struct PrepArgs {
  const float* src[8];
  u32* hi[8];
  u32* lo[8];
  int nblk[8];
};

__global__ __launch_bounds__(64) void prep_all_kernel(PrepArgs args) {
  int b = blockIdx.x;
  int e = 0;
  while (e < 8 && b >= args.nblk[e]) { b -= args.nblk[e]; e++; }
  if (e >= 8) return;  // grid/table miscount degrades to no-op, not a fault
  int l = threadIdx.x;
  u32 hi[4], lo[4];
  if (e < 7) {
    int m = b >> 3, s = (b >> 2) & 1, c = b & 3;
    int n  = c * 16 + (l & 15);
    int k0 = s * 32 + (l >> 4) * 8;
    const float* src = args.src[e] + (size_t)m * 4096;
#pragma unroll
    for (int p = 0; p < 4; p++) {
      float v0 = src[(k0 + 2 * p) * 64 + n];
      float v1 = src[(k0 + 2 * p + 1) * 64 + n];
      u32 h0 = rbf(v0), h1 = rbf(v1);
      float r0 = v0 - __uint_as_float(h0 << 16);
      float r1 = v1 - __uint_as_float(h1 << 16);
      hi[p] = h0 | (h1 << 16);
      lo[p] = rbf(r0) | (rbf(r1) << 16);
    }
    *(uint4*)(args.hi[e] + ((size_t)b * 64 + l) * 4) = make_uint4(hi[0], hi[1], hi[2], hi[3]);
    *(uint4*)(args.lo[e] + ((size_t)b * 64 + l) * 4) = make_uint4(lo[0], lo[1], lo[2], lo[3]);
  } else {
    int s = b >> 1, c = b & 1;
    int n  = c * 16 + (l & 15);
    int k0 = s * 32 + (l >> 4) * 8;
    const float* src = args.src[7];
#pragma unroll
    for (int p = 0; p < 4; p++) {
      float v0 = src[(k0 + 2 * p) * 32 + n];
      float v1 = src[(k0 + 2 * p + 1) * 32 + n];
      u32 h0 = rbf(v0), h1 = rbf(v1);
      float r0 = v0 - __uint_as_float(h0 << 16);
      float r1 = v1 - __uint_as_float(h1 << 16);
      hi[p] = h0 | (h1 << 16);
      lo[p] = rbf(r0) | (rbf(r1) << 16);
    }
    *(uint4*)(args.hi[7] + ((size_t)b * 64 + l) * 4) = make_uint4(hi[0], hi[1], hi[2], hi[3]);
    *(uint4*)(args.lo[7] + ((size_t)b * 64 + l) * 4) = make_uint4(lo[0], lo[1], lo[2], lo[3]);
  }
}

// frag offset (in u32) for kstep ks, colblock c (of 4), lane l
__device__ __forceinline__ size_t foff(int ks, int c, int l) {
  return ((size_t)((ks * 4 + c) * 64 + l)) * 4;
}
// frag offset for N=32 frags (2 colblocks)
__device__ __forceinline__ size_t foff32(int s, int c, int l) {
  return ((size_t)((s * 2 + c) * 64 + l)) * 4;
}

// ---------------- MFMA GEMM kernels: wave = 16 rows x 64 cols ----------------

__global__ __launch_bounds__(256) void sage_fused_kernel(
    int tm, int tu,
    const u32* __restrict__ agg_m, const u32* __restrict__ xm_prev, int sm_s,
    const u32* __restrict__ whiLm, const u32* __restrict__ wloLm,
    const u32* __restrict__ whiRm, const u32* __restrict__ wloRm,
    const float* __restrict__ bias_m, u32* __restrict__ out_m,
    const u32* __restrict__ agg_u, const u32* __restrict__ xu_prev, int su_s,
    const u32* __restrict__ whiLu, const u32* __restrict__ wloLu,
    const u32* __restrict__ whiRu, const u32* __restrict__ wloRu,
    const float* __restrict__ bias_u, u32* __restrict__ out_u) {
  int tile = blockIdx.x * 4 + (threadIdx.x >> 6);
  if (tile >= tm + tu) return;
  int lane = threadIdx.x & 63;
  const u32 *agg, *xin, *whiL, *wloL, *whiR, *wloR;
  const float* bias;
  u32* out;
  int xs;
  if (tile < tm) {
    agg = agg_m; xin = xm_prev; xs = sm_s;
    whiL = whiLm; wloL = wloLm; whiR = whiRm; wloR = wloRm;
    bias = bias_m; out = out_m;
  } else {
    tile -= tm;
    agg = agg_u; xin = xu_prev; xs = su_s;
    whiL = whiLu; wloL = wloLu; whiR = whiRu; wloR = wloRu;
    bias = bias_u; out = out_u;
  }
  int r  = tile * 16 + (lane & 15);
  int kq = lane >> 4;
  f32x4 acc[4];
#pragma unroll
  for (int c = 0; c < 4; c++) acc[c] = (f32x4){0.f, 0.f, 0.f, 0.f};
  const u32* arow0 = agg + (size_t)r * 32 + kq * 4;
  const u32* arow1 = xin + (size_t)r * xs + kq * 4;
#pragma unroll
  for (int s = 0; s < 2; s++) {
    bfrag a = *(const bfrag*)(arow0 + s * 16);
#pragma unroll
    for (int c = 0; c < 4; c++) {
      bfrag bh = *(const bfrag*)(whiL + foff(s, c, lane));
      bfrag bl = *(const bfrag*)(wloL + foff(s, c, lane));
      acc[c] = mfma16(a, bh, acc[c]);
      acc[c] = mfma16(a, bl, acc[c]);
    }
  }
#pragma unroll
  for (int s = 0; s < 2; s++) {
    bfrag a = *(const bfrag*)(arow1 + s * 16);
#pragma unroll
    for (int c = 0; c < 4; c++) {
      bfrag bh = *(const bfrag*)(whiR + foff(s, c, lane));
      bfrag bl = *(const bfrag*)(wloR + foff(s, c, lane));
      acc[c] = mfma16(a, bh, acc[c]);
      acc[c] = mfma16(a, bl, acc[c]);
    }
  }
  ushort_t* ob = (ushort_t*)out;
  int rowb = tile * 16 + (lane >> 4) * 4;
  int col0 = lane & 15;
#pragma unroll
  for (int c = 0; c < 4; c++) {
    float bb = bias[c * 16 + col0];
#pragma unroll
    for (int g = 0; g < 4; g++) {
      float v = fmaxf(acc[c][g] + bb, 0.f);
      ob[(size_t)(rowb + g) * 192 + c * 16 + col0] = (ushort_t)rbf(v);
    }
  }
}

__global__ __launch_bounds__(256) void proj_fused_kernel(
    int tu, int tm,
    const u32* __restrict__ xin_u, const u32* __restrict__ whi_u, const u32* __restrict__ wlo_u,
    const float* __restrict__ bias_u, u32* __restrict__ out_u,
    const u32* __restrict__ xin_m, const u32* __restrict__ whi_m, const u32* __restrict__ wlo_m,
    const float* __restrict__ bias_m, u32* __restrict__ out_m) {
  int tile = blockIdx.x * 4 + (threadIdx.x >> 6);
  if (tile >= tu + tm) return;
  int lane = threadIdx.x & 63;
  const u32 *xin, *whi, *wlo;
  const float* bias;
  u32* out;
  if (tile < tu) {
    xin = xin_u; whi = whi_u; wlo = wlo_u; bias = bias_u; out = out_u;
  } else {
    tile -= tu;
    xin = xin_m; whi = whi_m; wlo = wlo_m; bias = bias_m; out = out_m;
  }
  int r  = tile * 16 + (lane & 15);
  int kq = lane >> 4;
  f32x4 acc[4];
#pragma unroll
  for (int c = 0; c < 4; c++) acc[c] = (f32x4){0.f, 0.f, 0.f, 0.f};
  const u32* arow = xin + (size_t)r * 96 + kq * 4;
#pragma unroll
  for (int ks = 0; ks < 6; ks++) {
    bfrag a = *(const bfrag*)(arow + ks * 16);
#pragma unroll
    for (int c = 0; c < 4; c++) {
      bfrag bh = *(const bfrag*)(whi + foff(ks, c, lane));
      bfrag bl = *(const bfrag*)(wlo + foff(ks, c, lane));
      acc[c] = mfma16(a, bh, acc[c]);
      acc[c] = mfma16(a, bl, acc[c]);
    }
  }
  ushort_t* ob = (ushort_t*)out;
  int rowb = tile * 16 + (lane >> 4) * 4;
  int col0 = lane & 15;
#pragma unroll
  for (int c = 0; c < 4; c++) {
    float bb = bias[c * 16 + col0];
#pragma unroll
    for (int g = 0; g < 4; g++) {
      float v = acc[c][g] + bb;
      ob[(size_t)(rowb + g) * 64 + c * 16 + col0] = (ushort_t)rbf(v);
    }
  }
}

// y1 = cat(h_u[lu], h_m[lm]) @ W1 + b1; TWO tiles per wave (ntiles must be even).
__global__ __launch_bounds__(256) void cls1_mfma_kernel(
    int ntiles, const u32* __restrict__ hu, const u32* __restrict__ hm,
    const int* __restrict__ lu, const int* __restrict__ lm,
    const u32* __restrict__ whi, const u32* __restrict__ wlo,
    const float* __restrict__ b1, u32* __restrict__ y1) {
  int wid = blockIdx.x * 4 + (threadIdx.x >> 6);
  int t0 = wid * 2;
  if (t0 >= ntiles) return;  // ntiles even -> t0+1 also valid when t0 valid
  int lane = threadIdx.x & 63;
  int rit = lane & 15;
  int kq  = lane >> 4;
  int r0 = t0 * 16 + rit;
  int r1 = r0 + 16;
  int gu0 = lu[r0], gm0 = lm[r0];
  int gu1 = lu[r1], gm1 = lm[r1];
  f32x4 acc0[4], acc1[4];
#pragma unroll
  for (int c = 0; c < 4; c++) {
    acc0[c] = (f32x4){0.f, 0.f, 0.f, 0.f};
    acc1[c] = (f32x4){0.f, 0.f, 0.f, 0.f};
  }
  const u32* pu0 = hu + (size_t)gu0 * 32 + kq * 4;
  const u32* pm0 = hm + (size_t)gm0 * 32 + kq * 4;
  const u32* pu1 = hu + (size_t)gu1 * 32 + kq * 4;
  const u32* pm1 = hm + (size_t)gm1 * 32 + kq * 4;
#pragma unroll
  for (int s = 0; s < 2; s++) {
    bfrag au0 = *(const bfrag*)(pu0 + s * 16);
    bfrag au1 = *(const bfrag*)(pu1 + s * 16);
#pragma unroll
    for (int c = 0; c < 4; c++) {
      bfrag bh = *(const bfrag*)(whi + foff(s, c, lane));
      bfrag bl = *(const bfrag*)(wlo + foff(s, c, lane));
      acc0[c] = mfma16(au0, bh, acc0[c]);
      acc0[c] = mfma16(au0, bl, acc0[c]);
      acc1[c] = mfma16(au1, bh, acc1[c]);
      acc1[c] = mfma16(au1, bl, acc1[c]);
    }
  }
#pragma unroll
  for (int s = 0; s < 2; s++) {
    bfrag am0 = *(const bfrag*)(pm0 + s * 16);
    bfrag am1 = *(const bfrag*)(pm1 + s * 16);
#pragma unroll
    for (int c = 0; c < 4; c++) {
      bfrag bh = *(const bfrag*)(whi + foff(2 + s, c, lane));
      bfrag bl = *(const bfrag*)(wlo + foff(2 + s, c, lane));
      acc0[c] = mfma16(am0, bh, acc0[c]);
      acc0[c] = mfma16(am0, bl, acc0[c]);
      acc1[c] = mfma16(am1, bh, acc1[c]);
      acc1[c] = mfma16(am1, bl, acc1[c]);
    }
  }
  ushort_t* ob = (ushort_t*)y1;
  int col0 = lane & 15;
  int rowb0 = t0 * 16 + kq * 4;
  int rowb1 = rowb0 + 16;
#pragma unroll
  for (int c = 0; c < 4; c++) {
    float bb = b1[c * 16 + col0];
#pragma unroll
    for (int g = 0; g < 4; g++) {
      float v0 = acc0[c][g] + bb;
      float v1 = acc1[c][g] + bb;
      ob[(size_t)(rowb0 + g) * 64 + c * 16 + col0] = (ushort_t)rbf(v0);
      ob[(size_t)(rowb1 + g) * 64 + c * 16 + col0] = (ushort_t)rbf(v1);
    }
  }
}

// y2 = relu(BN1(y1)) @ W2 + b2 via MFMA; BN applied in-register to A-frags.
__global__ __launch_bounds__(256) void cls2_mfma_kernel(
    int ntiles, const u32* __restrict__ y1,
    const float* __restrict__ scale1, const float* __restrict__ shift1,
    const u32* __restrict__ whi, const u32* __restrict__ wlo,
    const float* __restrict__ b2, u32* __restrict__ y2) {
  int tile = blockIdx.x * 4 + (threadIdx.x >> 6);
  if (tile >= ntiles) return;
  int lane = threadIdx.x & 63;
  int r  = tile * 16 + (lane & 15);
  int kq = lane >> 4;
  f32x4 acc[2];
  acc[0] = (f32x4){0.f, 0.f, 0.f, 0.f};
  acc[1] = (f32x4){0.f, 0.f, 0.f, 0.f};
  const u32* xrow = y1 + (size_t)r * 32 + kq * 4;
#pragma unroll
  for (int s = 0; s < 2; s++) {
    uint4 q = *(const uint4*)(xrow + s * 16);
    int kb = s * 32 + kq * 8;
    float a0 = fmaxf(bflo(q.x) * scale1[kb + 0] + shift1[kb + 0], 0.f);
    float a1 = fmaxf(bfhi(q.x) * scale1[kb + 1] + shift1[kb + 1], 0.f);
    float a2 = fmaxf(bflo(q.y) * scale1[kb + 2] + shift1[kb + 2], 0.f);
    float a3 = fmaxf(bfhi(q.y) * scale1[kb + 3] + shift1[kb + 3], 0.f);
    float a4 = fmaxf(bflo(q.z) * scale1[kb + 4] + shift1[kb + 4], 0.f);
    float a5 = fmaxf(bfhi(q.z) * scale1[kb + 5] + shift1[kb + 5], 0.f);
    float a6 = fmaxf(bflo(q.w) * scale1[kb + 6] + shift1[kb + 6], 0.f);
    float a7 = fmaxf(bfhi(q.w) * scale1[kb + 7] + shift1[kb + 7], 0.f);
    uint4 pa = make_uint4(packbf(a0, a1), packbf(a2, a3), packbf(a4, a5), packbf(a6, a7));
    bfrag a = *(bfrag*)&pa;
#pragma unroll
    for (int c = 0; c < 2; c++) {
      bfrag bh = *(const bfrag*)(whi + foff32(s, c, lane));
      bfrag bl = *(const bfrag*)(wlo + foff32(s, c, lane));
      acc[c] = mfma16(a, bh, acc[c]);
      acc[c] = mfma16(a, bl, acc[c]);
    }
  }
  ushort_t* ob = (ushort_t*)y2;
  int rowb = tile * 16 + (lane >> 4) * 4;
  int col0 = lane & 15;
#pragma unroll
  for (int c = 0; c < 2; c++) {
    float bb = b2[c * 16 + col0];
#pragma unroll
    for (int g = 0; g < 4; g++) {
      float v = acc[c][g] + bb;
      ob[(size_t)(rowb + g) * 32 + c * 16 + col0] = (ushort_t)rbf(v);
    }
  }
}

// ---------------- BN stats (de-spilled streamer) / finalize / cls3 ----------------

template <int CU>
__global__ __launch_bounds__(256) void stats_fast_kernel(const u32* __restrict__ y, int nrows,
                                                         float* __restrict__ sum,
                                                         float* __restrict__ ssq) {
  constexpr int TPR = CU / 4;      // threads per row (one uint4 each)
  constexpr int RPI = 256 / TPR;   // rows per block per iteration
  int t = threadIdx.x;
  int q  = t % TPR;                // uint4 index within row (bf16 cols q*8..q*8+7)
  int rg = t / TPR;
  float4 sA = {0.f, 0.f, 0.f, 0.f}, sB = {0.f, 0.f, 0.f, 0.f};
  float4 qA = {0.f, 0.f, 0.f, 0.f}, qB = {0.f, 0.f, 0.f, 0.f};
  for (int row = blockIdx.x * RPI + rg; row < nrows; row += gridDim.x * RPI) {
    uint4 v = *(const uint4*)(y + (size_t)row * CU + q * 4);
    float a0 = bflo(v.x), a1 = bfhi(v.x), a2 = bflo(v.y), a3 = bfhi(v.y);
    float a4 = bflo(v.z), a5 = bfhi(v.z), a6 = bflo(v.w), a7 = bfhi(v.w);
    sA.x += a0; qA.x += a0 * a0;
    sA.y += a1; qA.y += a1 * a1;
    sA.z += a2; qA.z += a2 * a2;
    sA.w += a3; qA.w += a3 * a3;
    sB.x += a4; qB.x += a4 * a4;
    sB.y += a5; qB.y += a5 * a5;
    sB.z += a6; qB.z += a6 * a6;
    sB.w += a7; qB.w += a7 * a7;
  }
#pragma unroll
  for (int mask = TPR; mask < 64; mask <<= 1) {
    sA.x += __shfl_xor(sA.x, mask); sA.y += __shfl_xor(sA.y, mask);
    sA.z += __shfl_xor(sA.z, mask); sA.w += __shfl_xor(sA.w, mask);
    sB.x += __shfl_xor(sB.x, mask); sB.y += __shfl_xor(sB.y, mask);
    sB.z += __shfl_xor(sB.z, mask); sB.w += __shfl_xor(sB.w, mask);
    qA.x += __shfl_xor(qA.x, mask); qA.y += __shfl_xor(qA.y, mask);
    qA.z += __shfl_xor(qA.z, mask); qA.w += __shfl_xor(qA.w, mask);
    qB.x += __shfl_xor(qB.x, mask); qB.y += __shfl_xor(qB.y, mask);
    qB.z += __shfl_xor(qB.z, mask); qB.w += __shfl_xor(qB.w, mask);
  }
  __shared__ float part[4][TPR][16];
  int wv = t >> 6, lane = t & 63;
  if (lane < TPR) {
    float* p = part[wv][lane];
    p[0] = sA.x; p[1] = sA.y; p[2] = sA.z; p[3] = sA.w;
    p[4] = sB.x; p[5] = sB.y; p[6] = sB.z; p[7] = sB.w;
    p[8] = qA.x; p[9] = qA.y; p[10] = qA.z; p[11] = qA.w;
    p[12] = qB.x; p[13] = qB.y; p[14] = qB.z; p[15] = qB.w;
  }
  __syncthreads();
  if (t < TPR * 16) {
    int qq = t >> 4, j = t & 15;
    float v = part[0][qq][j] + part[1][qq][j] + part[2][qq][j] + part[3][qq][j];
    if (j < 8) atomicAdd(&sum[qq * 8 + j], v);
    else       atomicAdd(&ssq[qq * 8 + (j - 8)], v);
  }
}

__global__ void bn_finalize_kernel(const float* __restrict__ sum, const float* __restrict__ ssq,
                                   const float* __restrict__ g, const float* __restrict__ be,
                                   int ncols, float inv_n,
                                   float* __restrict__ scale, float* __restrict__ shift) {
  int t = threadIdx.x;
  if (t < ncols) {
    float m = sum[t] * inv_n;
    float v = ssq[t] * inv_n - m * m;   // biased variance, as torch BN training-mode
    float rstd = rsqrtf(v + BN_EPS);
    float sc = g[t] * rstd;
    scale[t] = sc;
    shift[t] = be[t] - m * sc;
  }
}

__global__ void cls3_kernel(const u32* __restrict__ y2, const float* __restrict__ scale2,
                            const float* __restrict__ shift2, const float* __restrict__ W3,
                            const float* __restrict__ b3, float* __restrict__ outp) {
  int r = blockIdx.x * 256 + threadIdx.x;
  if (r >= ELc) return;
  const u32* yr = y2 + (size_t)r * 16;
  float s = b3[0];
#pragma unroll
  for (int j = 0; j < 16; j++) {
    u32 u = yr[j];
    float v0 = fmaxf(bflo(u) * scale2[2 * j] + shift2[2 * j], 0.f);
    float v1 = fmaxf(bfhi(u) * scale2[2 * j + 1] + shift2[2 * j + 1], 0.f);
    s += v0 * W3[2 * j] + v1 * W3[2 * j + 1];
  }
  outp[r] = s;
}

}  // namespace

extern "C" void kernel_launch(void* const* d_in, const int* in_sizes, int n_in,
                              void* d_out, int out_size, void* d_ws, size_t ws_size,
                              hipStream_t stream) {
  const int*   n_id    = (const int*)d_in[0];
  const float* movie_x = (const float*)d_in[1];
  const int*   eu      = (const int*)d_in[2];
  const int*   em      = (const int*)d_in[3];
  const int*   lu      = (const int*)d_in[4];
  const int*   lm      = (const int*)d_in[5];
  const float* uemb    = (const float*)d_in[6];
  const float* Wl_um   = (const float*)d_in[7];
  const float* b_um    = (const float*)d_in[8];
  const float* Wr_um   = (const float*)d_in[9];
  const float* Wl_mu   = (const float*)d_in[10];
  const float* b_mu    = (const float*)d_in[11];
  const float* Wr_mu   = (const float*)d_in[12];
  const float* puW     = (const float*)d_in[13];
  const float* pub     = (const float*)d_in[14];
  const float* pmW     = (const float*)d_in[15];
  const float* pmb     = (const float*)d_in[16];
  const float* W1      = (const float*)d_in[17];
  const float* b1      = (const float*)d_in[18];
  const float* g1      = (const float*)d_in[19];
  const float* be1     = (const float*)d_in[20];
  const float* W2      = (const float*)d_in[21];
  const float* b2      = (const float*)d_in[22];
  const float* g2      = (const float*)d_in[23];
  const float* be2     = (const float*)d_in[24];
  const float* W3      = (const float*)d_in[25];
  const float* b3      = (const float*)d_in[26];
  float* outp = (float*)d_out;

  u32* ws = (u32*)d_ws;
  size_t o = 0;
  u32* xu0    = ws + o; o += (size_t)NUc * 32;
  u32* xm0    = ws + o; o += (size_t)NMc * 32;
  u32* outs_u = ws + o; o += (size_t)NUc * 96;
  u32* outs_m = ws + o; o += (size_t)NMc * 96;
  u32* agg_u  = ws + o; o += (size_t)NUc * 32;
  u32* agg_m  = ws + o; o += (size_t)NMc * 32;
  u32* y1 = ws;  // bf16 [EL][64] = 16M u32, overlays conv region (dead before cls1)
  u32* y2     = ws + o; o += (size_t)ELc * 16;
  u32* h_u    = ws + o; o += (size_t)NUc * 32;
  u32* h_m    = ws + o; o += (size_t)NMc * 32;
  int* su     = (int*)(ws + o); o += (size_t)NUc * CAPU;
  int* sm     = (int*)(ws + o); o += (size_t)NMc * CAPM;
  int* cnt_u  = (int*)(ws + o); o += NUc;        // cnt_u, cnt_m, stats contiguous:
  int* cnt_m  = (int*)(ws + o); o += NMc;        //   one memset covers all three
  float* stats = (float*)(ws + o); o += 512;
  u32* frWlum_h = ws + o; o += 3 * 2048;  u32* frWlum_l = ws + o; o += 3 * 2048;
  u32* frWrum_h = ws + o; o += 3 * 2048;  u32* frWrum_l = ws + o; o += 3 * 2048;
  u32* frWlmu_h = ws + o; o += 3 * 2048;  u32* frWlmu_l = ws + o; o += 3 * 2048;
  u32* frWrmu_h = ws + o; o += 3 * 2048;  u32* frWrmu_l = ws + o; o += 3 * 2048;
  u32* frPu_h   = ws + o; o += 3 * 2048;  u32* frPu_l   = ws + o; o += 3 * 2048;
  u32* frPm_h   = ws + o; o += 3 * 2048;  u32* frPm_l   = ws + o; o += 3 * 2048;
  u32* frW1_h   = ws + o; o += 2 * 2048;  u32* frW1_l   = ws + o; o += 2 * 2048;
  u32* frW2_h   = ws + o; o += 1024;      u32* frW2_l   = ws + o; o += 1024;
  if (ws_size < o * sizeof(u32)) return;  // ws too small -> leave zeros (diagnostic)

  float* sum1 = stats,        *ssq1 = stats + 64;
  float* sum2 = stats + 128,  *ssq2 = stats + 160;
  float* scale1 = stats + 192, *shift1 = stats + 256;
  float* scale2 = stats + 320, *shift2 = stats + 352;

  hipMemsetAsync(cnt_u, 0, (NUc + NMc + 192) * sizeof(int), stream);

  PrepArgs pa;
  pa.src[0] = Wl_um; pa.hi[0] = frWlum_h; pa.lo[0] = frWlum_l; pa.nblk[0] = 24;
  pa.src[1] = Wr_um; pa.hi[1] = frWrum_h; pa.lo[1] = frWrum_l; pa.nblk[1] = 24;
  pa.src[2] = Wl_mu; pa.hi[2] = frWlmu_h; pa.lo[2] = frWlmu_l; pa.nblk[2] = 24;
  pa.src[3] = Wr_mu; pa.hi[3] = frWrmu_h; pa.lo[3] = frWrmu_l; pa.nblk[3] = 24;
  pa.src[4] = puW;   pa.hi[4] = frPu_h;   pa.lo[4] = frPu_l;   pa.nblk[4] = 24;
  pa.src[5] = pmW;   pa.hi[5] = frPm_h;   pa.lo[5] = frPm_l;   pa.nblk[5] = 24;
  pa.src[6] = W1;    pa.hi[6] = frW1_h;   pa.lo[6] = frW1_l;   pa.nblk[6] = 16;
  pa.src[7] = W2;    pa.hi[7] = frW2_h;   pa.lo[7] = frW2_l;   pa.nblk[7] = 4;
  prep_all_kernel<<<PREP_BLOCKS, 64, 0, stream>>>(pa);

  int eb4 = (NE / 4 + 255) / 256;   // 4 edges per thread (NE % 4 == 0)
  for (int p = 0; p < NPASS; p++) {
    scatter_pass_kernel<<<eb4, 256, 0, stream>>>(
        eu, em, cnt_u, cnt_m, su, sm,
        p * (NUc / NPASS), (p + 1) * (NUc / NPASS),
        p * (NMc / NPASS), (p + 1) * (NMc / NPASS));
  }
  gatherconv_kernel<<<((NUc + NMc) * 8 + 255) / 256, 256, 0, stream>>>(
      n_id, uemb, xu0, movie_x, xm0);

  int tu = NUc / 16, tm = NMc / 16;   // 6250, 1250 (exact)
  int agg_grid = ((NMc + NUc) * 64 + 255) / 256;
  for (int i = 0; i < NL; i++) {
    const u32* xu_prev = (i == 0) ? xu0 : (outs_u + (size_t)(i - 1) * 32);
    const u32* xm_prev = (i == 0) ? xm0 : (outs_m + (size_t)(i - 1) * 32);
    int su_s = (i == 0) ? 32 : 96;
    int sm_s = (i == 0) ? 32 : 96;
    aggregate_fused_kernel<<<agg_grid, 256, 0, stream>>>(
        cnt_m, sm, xu_prev, su_s, agg_m,
        cnt_u, su, xm_prev, sm_s, agg_u);
    sage_fused_kernel<<<(tm + tu + 3) / 4, 256, 0, stream>>>(
        tm, tu,
        agg_m, xm_prev, sm_s,
        frWlum_h + (size_t)i * 2048, frWlum_l + (size_t)i * 2048,
        frWrum_h + (size_t)i * 2048, frWrum_l + (size_t)i * 2048,
        b_um + (size_t)i * HD, outs_m + (size_t)i * 32,
        agg_u, xu_prev, su_s,
        frWlmu_h + (size_t)i * 2048, frWlmu_l + (size_t)i * 2048,
        frWrmu_h + (size_t)i * 2048, frWrmu_l + (size_t)i * 2048,
        b_mu + (size_t)i * HD, outs_u + (size_t)i * 32);
  }

  proj_fused_kernel<<<(tu + tm + 3) / 4, 256, 0, stream>>>(
      tu, tm, outs_u, frPu_h, frPu_l, pub, h_u,
      outs_m, frPm_h, frPm_l, pmb, h_m);

  int tl = ELc / 16;  // 31250 (exact, even)
  cls1_mfma_kernel<<<(tl / 2 + 3) / 4, 256, 0, stream>>>(tl, h_u, h_m, lu, lm, frW1_h, frW1_l, b1, y1);
  stats_fast_kernel<32><<<STATS_BLOCKS, 256, 0, stream>>>(y1, ELc, sum1, ssq1);
  bn_finalize_kernel<<<1, 64, 0, stream>>>(sum1, ssq1, g1, be1, 64, 1.f / ELc, scale1, shift1);
  cls2_mfma_kernel<<<(tl + 3) / 4, 256, 0, stream>>>(tl, y1, scale1, shift1, frW2_h, frW2_l, b2, y2);
  stats_fast_kernel<16><<<STATS_BLOCKS, 256, 0, stream>>>(y2, ELc, sum2, ssq2);
  bn_finalize_kernel<<<1, 64, 0, stream>>>(sum2, ssq2, g2, be2, 32, 1.f / ELc, scale2, shift2);
  cls3_kernel<<<(ELc + 255) / 256, 256, 0, stream>>>(y2, scale2, shift2, W3, b3, outp);
}